// Round 7
// baseline (181.569 us; speedup 1.0000x reference)
//
#include <hip/hip_runtime.h>
#include <math.h>

#define EPS 1e-6f

constexpr int BLOCK = 256;
constexpr int GRID  = 2048;

typedef int   vi4 __attribute__((ext_vector_type(4)));
typedef float vf4 __attribute__((ext_vector_type(4)));

// Stage 0: pad x [V,3] -> xp [V] float4; also zero the output scalar and the
// block-completion ticket counter (must be re-zeroed every call: the harness
// does not re-initialize d_ws between graph replays).
__global__ __launch_bounds__(BLOCK) void pad_vertices(
    const float* __restrict__ x,
    vf4* __restrict__ xp,
    float* __restrict__ out,
    unsigned int* __restrict__ counter,
    int nverts)
{
    int v = blockIdx.x * BLOCK + threadIdx.x;
    if (v < nverts) {
        const float* p = x + 3 * v;
        vf4 t = {p[0], p[1], p[2], 0.f};
        xp[v] = t;
    }
    if (v == 0) { out[0] = 0.f; counter[0] = 0u; }
}

// Stage 1: per-block partial sums; last finishing block reduces all partials.
__global__ __launch_bounds__(BLOCK) void spring_energy_partial(
    const vf4*   __restrict__ xp,
    const float* __restrict__ l0,
    const float* __restrict__ k,
    const int*   __restrict__ idx,
    float* __restrict__ partials,
    unsigned int* __restrict__ counter,
    float* __restrict__ out,
    int nsprings)
{
    const int tid      = blockIdx.x * BLOCK + threadIdx.x;
    const int nthreads = GRID * BLOCK;
    const int nquads   = nsprings >> 2;   // 4 springs per iteration

    float acc = 0.f;
    for (int q = tid; q < nquads; q += nthreads) {
        const int s = q << 2;
        vi4 ia  = __builtin_nontemporal_load(reinterpret_cast<const vi4*>(idx + 2 * s));
        vi4 ib  = __builtin_nontemporal_load(reinterpret_cast<const vi4*>(idx + 2 * s) + 1);
        vf4 l0v = __builtin_nontemporal_load(reinterpret_cast<const vf4*>(l0 + s));
        vf4 kv  = __builtin_nontemporal_load(reinterpret_cast<const vf4*>(k + s));

        const vf4* p0 = xp + ia.x;  const vf4* p1 = xp + ia.y;
        const vf4* p2 = xp + ia.z;  const vf4* p3 = xp + ia.w;
        const vf4* p4 = xp + ib.x;  const vf4* p5 = xp + ib.y;
        const vf4* p6 = xp + ib.z;  const vf4* p7 = xp + ib.w;

        vf4 a0, b0, a1, b1, a2, b2, a3, b3;
        asm volatile(
            "global_load_dwordx4 %0, %8, off sc0\n\t"
            "global_load_dwordx4 %1, %9, off sc0\n\t"
            "global_load_dwordx4 %2, %10, off sc0\n\t"
            "global_load_dwordx4 %3, %11, off sc0\n\t"
            "global_load_dwordx4 %4, %12, off sc0\n\t"
            "global_load_dwordx4 %5, %13, off sc0\n\t"
            "global_load_dwordx4 %6, %14, off sc0\n\t"
            "global_load_dwordx4 %7, %15, off sc0\n\t"
            "s_waitcnt vmcnt(0)"
            : "=&v"(a0), "=&v"(b0), "=&v"(a1), "=&v"(b1),
              "=&v"(a2), "=&v"(b2), "=&v"(a3), "=&v"(b3)
            : "v"(p0), "v"(p1), "v"(p2), "v"(p3),
              "v"(p4), "v"(p5), "v"(p6), "v"(p7)
            : "memory");

        float dx, dy, dz, qd, l, dl;

        dx = a0.x - b0.x; dy = a0.y - b0.y; dz = a0.z - b0.z;
        qd = dx*dx + dy*dy + dz*dz;
        l  = sqrtf(qd + EPS); dl = l - l0v.x;
        acc = fmaf(kv.x * dl, dl, acc);

        dx = a1.x - b1.x; dy = a1.y - b1.y; dz = a1.z - b1.z;
        qd = dx*dx + dy*dy + dz*dz;
        l  = sqrtf(qd + EPS); dl = l - l0v.y;
        acc = fmaf(kv.y * dl, dl, acc);

        dx = a2.x - b2.x; dy = a2.y - b2.y; dz = a2.z - b2.z;
        qd = dx*dx + dy*dy + dz*dz;
        l  = sqrtf(qd + EPS); dl = l - l0v.z;
        acc = fmaf(kv.z * dl, dl, acc);

        dx = a3.x - b3.x; dy = a3.y - b3.y; dz = a3.z - b3.z;
        qd = dx*dx + dy*dy + dz*dz;
        l  = sqrtf(qd + EPS); dl = l - l0v.w;
        acc = fmaf(kv.w * dl, dl, acc);
    }

    // scalar tail (nsprings % 4 — zero for E=6.4M, kept for generality)
    if (blockIdx.x == 0) {
        for (int s = (nquads << 2) + threadIdx.x; s < nsprings; s += BLOCK) {
            int i1 = idx[2 * s], i2 = idx[2 * s + 1];
            vf4 a = xp[i1], b = xp[i2];
            float dx = a.x - b.x, dy = a.y - b.y, dz = a.z - b.z;
            float l  = sqrtf(dx*dx + dy*dy + dz*dz + EPS);
            float dl = l - l0[s];
            acc = fmaf(k[s] * dl, dl, acc);
        }
    }

    // wave (64-lane) reduction
    #pragma unroll
    for (int off = 32; off > 0; off >>= 1)
        acc += __shfl_down(acc, off, 64);

    __shared__ float wsum[BLOCK / 64];
    const int lane = threadIdx.x & 63;
    const int wid  = threadIdx.x >> 6;
    if (lane == 0) wsum[wid] = acc;
    __syncthreads();

    __shared__ unsigned int ticket_s;
    if (threadIdx.x == 0) {
        partials[blockIdx.x] = wsum[0] + wsum[1] + wsum[2] + wsum[3];
        __threadfence();                              // publish partial (device scope)
        ticket_s = atomicAdd(counter, 1u);            // device-scope by default
    }
    __syncthreads();

    // last block to finish reduces all partials (saves a kernel launch)
    if (ticket_s == GRID - 1) {
        __threadfence();                              // acquire: see all partials
        float facc = 0.f;
        for (int i = threadIdx.x; i < GRID; i += BLOCK)
            facc += partials[i];
        #pragma unroll
        for (int off = 32; off > 0; off >>= 1)
            facc += __shfl_down(facc, off, 64);
        if (lane == 0) wsum[wid] = facc;
        __syncthreads();
        if (threadIdx.x == 0)
            out[0] = 0.5f * (wsum[0] + wsum[1] + wsum[2] + wsum[3]);
    }
}

extern "C" void kernel_launch(void* const* d_in, const int* in_sizes, int n_in,
                              void* d_out, int out_size, void* d_ws, size_t ws_size,
                              hipStream_t stream) {
    // setup_inputs() order: x [V,3] f32, l0 [E] f32, k [E] f32, indices [E,2] i32
    const float* x   = (const float*)d_in[0];
    const float* l0  = (const float*)d_in[1];
    const float* k   = (const float*)d_in[2];
    const int*   idx = (const int*)  d_in[3];
    float* out       = (float*)d_out;

    const int nverts   = in_sizes[0] / 3;   // V = 100,000
    const int nsprings = in_sizes[1];       // E = 6,400,000

    // d_ws layout: [xp: nverts float4][partials: GRID floats][counter: 1 u32]
    vf4*          xp       = (vf4*)d_ws;
    float*        partials = (float*)((char*)d_ws + (size_t)nverts * sizeof(vf4));
    unsigned int* counter  = (unsigned int*)(partials + GRID);

    pad_vertices<<<(nverts + BLOCK - 1) / BLOCK, BLOCK, 0, stream>>>(
        x, xp, out, counter, nverts);
    spring_energy_partial<<<GRID, BLOCK, 0, stream>>>(
        xp, l0, k, idx, partials, counter, out, nsprings);
}

// Round 8
// 80.627 us; speedup vs baseline: 2.2520x; 2.2520x over previous
//
#include <hip/hip_runtime.h>
#include <math.h>

#define EPS 1e-6f

constexpr int BLOCK = 256;
constexpr int GRID  = 2048;

typedef int   vi4 __attribute__((ext_vector_type(4)));
typedef float vf4 __attribute__((ext_vector_type(4)));

// Stage 1: per-block partial sums of k*dl*dl, 8 springs per iteration.
// Gathers read x [V,3] directly: 3 dword loads per endpoint. The 2nd/3rd
// dword of an endpoint hit the L1 line filled by the 1st -> in the warm
// (timed) regime this beats float4/fp16 repacks, and it needs no pad kernel.
__global__ __launch_bounds__(BLOCK) void spring_energy_partial(
    const float* __restrict__ x,
    const float* __restrict__ l0,
    const float* __restrict__ k,
    const int*   __restrict__ idx,
    float* __restrict__ partials,
    int nsprings)
{
    const int tid      = blockIdx.x * BLOCK + threadIdx.x;
    const int nthreads = GRID * BLOCK;
    const int nocts    = nsprings >> 3;   // 8 springs per iteration

    float acc = 0.f;
    for (int o = tid; o < nocts; o += nthreads) {
        const int s = o << 3;
        // streaming loads (nontemporal: keep x resident in caches)
        const vi4* ip = reinterpret_cast<const vi4*>(idx + 2 * s);
        vi4 i0 = __builtin_nontemporal_load(ip);
        vi4 i1 = __builtin_nontemporal_load(ip + 1);
        vi4 i2 = __builtin_nontemporal_load(ip + 2);
        vi4 i3 = __builtin_nontemporal_load(ip + 3);
        const vf4* lp = reinterpret_cast<const vf4*>(l0 + s);
        vf4 la = __builtin_nontemporal_load(lp);
        vf4 lb = __builtin_nontemporal_load(lp + 1);
        const vf4* kp = reinterpret_cast<const vf4*>(k + s);
        vf4 ka = __builtin_nontemporal_load(kp);
        vf4 kb = __builtin_nontemporal_load(kp + 1);

        const int ii[16] = {i0.x, i0.y, i0.z, i0.w, i1.x, i1.y, i1.z, i1.w,
                            i2.x, i2.y, i2.z, i2.w, i3.x, i3.y, i3.z, i3.w};

        // 16 endpoints x 3 dwords, all loads independent -> deep MLP
        float px[16], py[16], pz[16];
        #pragma unroll
        for (int j = 0; j < 16; ++j) {
            const float* p = x + 3 * ii[j];
            px[j] = p[0]; py[j] = p[1]; pz[j] = p[2];
        }

        const float lv[8] = {la.x, la.y, la.z, la.w, lb.x, lb.y, lb.z, lb.w};
        const float kv[8] = {ka.x, ka.y, ka.z, ka.w, kb.x, kb.y, kb.z, kb.w};

        #pragma unroll
        for (int j = 0; j < 8; ++j) {
            float dx = px[2*j] - px[2*j+1];
            float dy = py[2*j] - py[2*j+1];
            float dz = pz[2*j] - pz[2*j+1];
            float qd = dx*dx + dy*dy + dz*dz;
            float l  = sqrtf(qd + EPS);
            float dl = l - lv[j];
            acc = fmaf(kv[j] * dl, dl, acc);
        }
    }

    // scalar tail (nsprings % 8 — zero for E=6.4M, kept for generality)
    if (blockIdx.x == 0) {
        for (int s = (nocts << 3) + threadIdx.x; s < nsprings; s += BLOCK) {
            int a = idx[2 * s], b = idx[2 * s + 1];
            float dx = x[3*a]   - x[3*b];
            float dy = x[3*a+1] - x[3*b+1];
            float dz = x[3*a+2] - x[3*b+2];
            float l  = sqrtf(dx*dx + dy*dy + dz*dz + EPS);
            float dl = l - l0[s];
            acc = fmaf(k[s] * dl, dl, acc);
        }
    }

    // wave (64-lane) reduction
    #pragma unroll
    for (int off = 32; off > 0; off >>= 1)
        acc += __shfl_down(acc, off, 64);

    __shared__ float wsum[BLOCK / 64];
    const int lane = threadIdx.x & 63;
    const int wid  = threadIdx.x >> 6;
    if (lane == 0) wsum[wid] = acc;
    __syncthreads();
    if (threadIdx.x == 0)
        partials[blockIdx.x] = wsum[0] + wsum[1] + wsum[2] + wsum[3];
}

// Stage 2: deterministic final reduction of GRID partials -> scalar energy.
__global__ __launch_bounds__(BLOCK) void spring_energy_final(
    const float* __restrict__ partials,
    float* __restrict__ out)
{
    float acc = 0.f;
    for (int i = threadIdx.x; i < GRID; i += BLOCK)
        acc += partials[i];

    #pragma unroll
    for (int off = 32; off > 0; off >>= 1)
        acc += __shfl_down(acc, off, 64);

    __shared__ float wsum[BLOCK / 64];
    const int lane = threadIdx.x & 63;
    const int wid  = threadIdx.x >> 6;
    if (lane == 0) wsum[wid] = acc;
    __syncthreads();
    if (threadIdx.x == 0)
        out[0] = 0.5f * (wsum[0] + wsum[1] + wsum[2] + wsum[3]);
}

extern "C" void kernel_launch(void* const* d_in, const int* in_sizes, int n_in,
                              void* d_out, int out_size, void* d_ws, size_t ws_size,
                              hipStream_t stream) {
    // setup_inputs() order: x [V,3] f32, l0 [E] f32, k [E] f32, indices [E,2] i32
    const float* x   = (const float*)d_in[0];
    const float* l0  = (const float*)d_in[1];
    const float* k   = (const float*)d_in[2];
    const int*   idx = (const int*)  d_in[3];
    float* out       = (float*)d_out;
    float* partials  = (float*)d_ws;   // GRID floats = 8 KB scratch

    const int nsprings = in_sizes[1];  // E = 6,400,000

    spring_energy_partial<<<GRID, BLOCK, 0, stream>>>(x, l0, k, idx, partials, nsprings);
    spring_energy_final<<<1, BLOCK, 0, stream>>>(partials, out);
}

// Round 9
// 69.815 us; speedup vs baseline: 2.6007x; 1.1549x over previous
//
#include <hip/hip_runtime.h>
#include <math.h>

#define EPS 1e-6f

constexpr int BLOCK = 256;
constexpr int GRID  = 1600;   // 409,600 threads; 1.6M quads -> ~4 iters/thread, no 5% straggler tail

typedef int   vi4 __attribute__((ext_vector_type(4)));
typedef float vf4 __attribute__((ext_vector_type(4)));

// Per-block partial sums of k*dl*dl, 4 springs per iteration.
// Gathers read x [V,3] directly: 3 dword loads per endpoint; dwords 2-3 hit
// the L1 line filled by dword 1. Leanest variant (VGPR ~28) — measured best
// in the warm (timed) regime. The wall is L1 miss-handling throughput:
// ~2 unique lines/spring at ~3.3 cyc/line/CU, insensitive to format/bypass.
__global__ __launch_bounds__(BLOCK) void spring_energy_partial(
    const float* __restrict__ x,
    const float* __restrict__ l0,
    const float* __restrict__ k,
    const int*   __restrict__ idx,
    float* __restrict__ partials,
    int nsprings)
{
    const int tid      = blockIdx.x * BLOCK + threadIdx.x;
    const int nthreads = GRID * BLOCK;
    const int nquads   = nsprings >> 2;

    float acc = 0.f;
    for (int q = tid; q < nquads; q += nthreads) {
        const int s = q << 2;
        vi4 ia  = *reinterpret_cast<const vi4*>(idx + 2 * s);
        vi4 ib  = *reinterpret_cast<const vi4*>(idx + 2 * s + 4);
        vf4 l0v = *reinterpret_cast<const vf4*>(l0 + s);
        vf4 kv  = *reinterpret_cast<const vf4*>(k + s);

        const int i1[4] = {ia.x, ia.z, ib.x, ib.z};
        const int i2[4] = {ia.y, ia.w, ib.y, ib.w};
        const float lv[4] = {l0v.x, l0v.y, l0v.z, l0v.w};
        const float kvv[4]= {kv.x,  kv.y,  kv.z,  kv.w};

        #pragma unroll
        for (int j = 0; j < 4; ++j) {
            const float* p1 = x + 3 * i1[j];
            const float* p2 = x + 3 * i2[j];
            float dx = p1[0] - p2[0];
            float dy = p1[1] - p2[1];
            float dz = p1[2] - p2[2];
            float qd = dx*dx + dy*dy + dz*dz;
            float l  = sqrtf(qd + EPS);
            float dl = l - lv[j];
            acc = fmaf(kvv[j] * dl, dl, acc);
        }
    }

    // scalar tail (nsprings % 4 — zero for E=6.4M, kept for generality)
    if (blockIdx.x == 0) {
        for (int s = (nquads << 2) + threadIdx.x; s < nsprings; s += BLOCK) {
            int a = idx[2 * s], b = idx[2 * s + 1];
            float dx = x[3*a]   - x[3*b];
            float dy = x[3*a+1] - x[3*b+1];
            float dz = x[3*a+2] - x[3*b+2];
            float l  = sqrtf(dx*dx + dy*dy + dz*dz + EPS);
            float dl = l - l0[s];
            acc = fmaf(k[s] * dl, dl, acc);
        }
    }

    // wave (64-lane) reduction
    #pragma unroll
    for (int off = 32; off > 0; off >>= 1)
        acc += __shfl_down(acc, off, 64);

    __shared__ float wsum[BLOCK / 64];
    const int lane = threadIdx.x & 63;
    const int wid  = threadIdx.x >> 6;
    if (lane == 0) wsum[wid] = acc;
    __syncthreads();
    if (threadIdx.x == 0)
        partials[blockIdx.x] = wsum[0] + wsum[1] + wsum[2] + wsum[3];
}

// Deterministic final reduction of GRID partials -> scalar energy.
__global__ __launch_bounds__(BLOCK) void spring_energy_final(
    const float* __restrict__ partials,
    float* __restrict__ out)
{
    float acc = 0.f;
    for (int i = threadIdx.x; i < GRID; i += BLOCK)
        acc += partials[i];

    #pragma unroll
    for (int off = 32; off > 0; off >>= 1)
        acc += __shfl_down(acc, off, 64);

    __shared__ float wsum[BLOCK / 64];
    const int lane = threadIdx.x & 63;
    const int wid  = threadIdx.x >> 6;
    if (lane == 0) wsum[wid] = acc;
    __syncthreads();
    if (threadIdx.x == 0)
        out[0] = 0.5f * (wsum[0] + wsum[1] + wsum[2] + wsum[3]);
}

extern "C" void kernel_launch(void* const* d_in, const int* in_sizes, int n_in,
                              void* d_out, int out_size, void* d_ws, size_t ws_size,
                              hipStream_t stream) {
    // setup_inputs() order: x [V,3] f32, l0 [E] f32, k [E] f32, indices [E,2] i32
    const float* x   = (const float*)d_in[0];
    const float* l0  = (const float*)d_in[1];
    const float* k   = (const float*)d_in[2];
    const int*   idx = (const int*)  d_in[3];
    float* out       = (float*)d_out;
    float* partials  = (float*)d_ws;   // GRID floats of scratch

    const int nsprings = in_sizes[1];  // E = 6,400,000

    spring_energy_partial<<<GRID, BLOCK, 0, stream>>>(x, l0, k, idx, partials, nsprings);
    spring_energy_final<<<1, BLOCK, 0, stream>>>(partials, out);
}